// Round 6
// baseline (115.405 us; speedup 1.0000x reference)
//
#include <hip/hip_runtime.h>
#include <stdint.h>

#define BATCH 128
#define VOCAB 128000
#define TPB 256
#define JCH 5                                // float4 groups per thread
#define BLOCK_COLS (TPB * 4 * JCH)           // 5120
#define BPR (VOCAB / BLOCK_COLS)             // 25 blocks per row
#define GRID_A (BATCH * BPR)                 // 3200

__device__ __forceinline__ uint32_t rotl(uint32_t x, int r) {
#if __has_builtin(__builtin_rotateleft32)
  return __builtin_rotateleft32(x, (uint32_t)r);
#else
  return (x << r) | (x >> (32 - r));
#endif
}

// JAX threefry2x32, key=(0,42), partitionable: out = x0^x1 for ctr=(0,i).
// Input: x1 = i + 42 (key-add prefolded). x0 starts 0 so round-1 add = copy.
__device__ __forceinline__ uint32_t tf_from_init(uint32_t x1) {
  uint32_t x0 = x1;
  x1 = rotl(x1, 13) ^ x0;
  x0 += x1; x1 = rotl(x1, 15) ^ x0;
  x0 += x1; x1 = rotl(x1, 26) ^ x0;
  x0 += x1; x1 = rotl(x1,  6) ^ x0;
  x0 += 42u;          x1 += 0x1BD11BF1u;  // ks1, ks2+1
  x0 += x1; x1 = rotl(x1, 17) ^ x0;
  x0 += x1; x1 = rotl(x1, 29) ^ x0;
  x0 += x1; x1 = rotl(x1, 16) ^ x0;
  x0 += x1; x1 = rotl(x1, 24) ^ x0;
  x0 += 0x1BD11BF0u;  x1 += 2u;           // ks2, ks0+2
  x0 += x1; x1 = rotl(x1, 13) ^ x0;
  x0 += x1; x1 = rotl(x1, 15) ^ x0;
  x0 += x1; x1 = rotl(x1, 26) ^ x0;
  x0 += x1; x1 = rotl(x1,  6) ^ x0;
  /* ks0 = 0 */       x1 += 45u;          // ks1+3
  x0 += x1; x1 = rotl(x1, 17) ^ x0;
  x0 += x1; x1 = rotl(x1, 29) ^ x0;
  x0 += x1; x1 = rotl(x1, 16) ^ x0;
  x0 += x1; x1 = rotl(x1, 24) ^ x0;
  x0 += 42u;          x1 += 0x1BD11BF4u;  // ks1, ks2+4
  x0 += x1; x1 = rotl(x1, 13) ^ x0;
  x0 += x1; x1 = rotl(x1, 15) ^ x0;
  x0 += x1; x1 = rotl(x1, 26) ^ x0;
  x0 += x1; x1 = rotl(x1,  6) ^ x0;
  x0 += 0x1BD11BF0u;  x1 += 5u;           // ks2, ks0+5
  return x0 ^ x1;
}

// score = sp - ln2*log2(-log2(2-f)), sp = s*invT - ln(ln2). Bit-exact vs ref
// (absmax 0, rounds 1-4). Zero-mantissa draw -> +inf (wins).
__device__ __forceinline__ float score_one(uint32_t bits, float sp) {
  uint32_t fb = (bits >> 9) | 0x3F800000u;
  float q = 2.0f - __uint_as_float(fb);
  float t = __log2f(q);
  float l = __log2f(-t);                       // neg = free input modifier
  return __builtin_fmaf(l, -0.69314718f, sp);
}

__device__ __forceinline__ uint32_t order_f32(float sc) {
  uint32_t m = __float_as_uint(sc);
  return m ^ (uint32_t)(((int32_t)m >> 31) | 0x80000000);
}

#define SCORE(av, bv, JK)                                          \
  {                                                                \
    float sp = __builtin_fmaf((av), invT, 0.36651292f);            \
    float sc = score_one((bv), sp);                                \
    bestJK = (sc > bestS) ? (uint32_t)(JK) : bestJK;               \
    bestS = fmaxf(bestS, sc);                                      \
  }

__global__ __launch_bounds__(TPB, 4) void sample_main(
    const float* __restrict__ logits, const float* __restrict__ temps,
    unsigned long long* __restrict__ part) {
  const int b   = blockIdx.x;
  const int row = b / BPR;
  const int cb  = b - row * BPR;
  const int tcol = cb * BLOCK_COLS + (int)threadIdx.x * 4;

  const float invT = 1.0f / temps[row];
  const float* p0 = logits + (size_t)row * VOCAB + tcol;

  // Phase A: issue all loads (named scalars, no indexed arrays)
  const float4 a0 = *reinterpret_cast<const float4*>(p0);
  const float4 a1 = *reinterpret_cast<const float4*>(p0 + 1024);
  const float4 a2 = *reinterpret_cast<const float4*>(p0 + 2048);
  const float4 a3 = *reinterpret_cast<const float4*>(p0 + 3072);
  const float4 a4 = *reinterpret_cast<const float4*>(p0 + 4096);

  const uint32_t c42 = (uint32_t)row * (uint32_t)VOCAB + (uint32_t)tcol + 42u;

  // Phase B: all 20 threefry draws — independent of the loads, ~1400 VALU
  // instrs of latency cover + 20 independent chains of ILP.
  const uint32_t b0  = tf_from_init(c42 + 0u);
  const uint32_t b1  = tf_from_init(c42 + 1u);
  const uint32_t b2  = tf_from_init(c42 + 2u);
  const uint32_t b3  = tf_from_init(c42 + 3u);
  const uint32_t b4  = tf_from_init(c42 + 1024u);
  const uint32_t b5  = tf_from_init(c42 + 1025u);
  const uint32_t b6  = tf_from_init(c42 + 1026u);
  const uint32_t b7  = tf_from_init(c42 + 1027u);
  const uint32_t b8  = tf_from_init(c42 + 2048u);
  const uint32_t b9  = tf_from_init(c42 + 2049u);
  const uint32_t b10 = tf_from_init(c42 + 2050u);
  const uint32_t b11 = tf_from_init(c42 + 2051u);
  const uint32_t b12 = tf_from_init(c42 + 3072u);
  const uint32_t b13 = tf_from_init(c42 + 3073u);
  const uint32_t b14 = tf_from_init(c42 + 3074u);
  const uint32_t b15 = tf_from_init(c42 + 3075u);
  const uint32_t b16 = tf_from_init(c42 + 4096u);
  const uint32_t b17 = tf_from_init(c42 + 4097u);
  const uint32_t b18 = tf_from_init(c42 + 4098u);
  const uint32_t b19 = tf_from_init(c42 + 4099u);

  // Phase C: scores + running argmax (strict >: earliest col wins ties)
  float bestS = -__builtin_inff();
  uint32_t bestJK = 0u;
  SCORE(a0.x, b0,  0)  SCORE(a0.y, b1,  1)  SCORE(a0.z, b2,  2)  SCORE(a0.w, b3,  3)
  SCORE(a1.x, b4,  4)  SCORE(a1.y, b5,  5)  SCORE(a1.z, b6,  6)  SCORE(a1.w, b7,  7)
  SCORE(a2.x, b8,  8)  SCORE(a2.y, b9,  9)  SCORE(a2.z, b10, 10) SCORE(a2.w, b11, 11)
  SCORE(a3.x, b12, 12) SCORE(a3.y, b13, 13) SCORE(a3.z, b14, 14) SCORE(a3.w, b15, 15)
  SCORE(a4.x, b16, 16) SCORE(a4.y, b17, 17) SCORE(a4.z, b18, 18) SCORE(a4.w, b19, 19)

  // reconstruct winning column; pack (orderable score, ~col)
  const uint32_t col = (uint32_t)tcol + ((bestJK >> 2) << 10) + (bestJK & 3u);
  unsigned long long p =
      ((unsigned long long)order_f32(bestS) << 32) | (uint32_t)(~col);

#pragma unroll
  for (int off = 32; off > 0; off >>= 1) {
    unsigned long long o = __shfl_down(p, off, 64);
    p = (o > p) ? o : p;
  }

  __shared__ unsigned long long sm[TPB / 64];
  if ((threadIdx.x & 63) == 0) sm[threadIdx.x >> 6] = p;
  __syncthreads();
  if (threadIdx.x == 0) {
    unsigned long long bv = sm[0];
    bv = (sm[1] > bv) ? sm[1] : bv;
    bv = (sm[2] > bv) ? sm[2] : bv;
    bv = (sm[3] > bv) ? sm[3] : bv;
    part[b] = bv;
  }
}

__global__ __launch_bounds__(64) void reduce_rows(
    const unsigned long long* __restrict__ part, int* __restrict__ out) {
  const int r = blockIdx.x;
  const int t = threadIdx.x;
  unsigned long long bv = (t < BPR) ? part[r * BPR + t] : 0ull;
#pragma unroll
  for (int off = 32; off > 0; off >>= 1) {
    unsigned long long o = __shfl_down(bv, off, 64);
    bv = (o > bv) ? o : bv;
  }
  if (t == 0) out[r] = (int)(~(uint32_t)(bv & 0xFFFFFFFFull));
}

extern "C" void kernel_launch(void* const* d_in, const int* in_sizes, int n_in,
                              void* d_out, int out_size, void* d_ws, size_t ws_size,
                              hipStream_t stream) {
  const float* logits = (const float*)d_in[0];
  const float* temps  = (const float*)d_in[1];
  unsigned long long* part = (unsigned long long*)d_ws;  // 3200*8B = 25.6 KB
  int* out = (int*)d_out;

  hipLaunchKernelGGL(sample_main, dim3(GRID_A), dim3(TPB), 0, stream,
                     logits, temps, part);
  hipLaunchKernelGGL(reduce_rows, dim3(BATCH), dim3(64), 0, stream, part, out);
}

// Round 7
// 114.454 us; speedup vs baseline: 1.0083x; 1.0083x over previous
//
#include <hip/hip_runtime.h>
#include <stdint.h>

#define BATCH 128
#define VOCAB 128000
#define TPB 256
#define JCH 5                                // float4 groups per thread
#define BLOCK_COLS (TPB * 4 * JCH)           // 5120
#define BPR (VOCAB / BLOCK_COLS)             // 25 blocks per row
#define GRID_A (BATCH * BPR)                 // 3200

__device__ __forceinline__ uint32_t rotl(uint32_t x, int r) {
#if __has_builtin(__builtin_rotateleft32)
  return __builtin_rotateleft32(x, (uint32_t)r);
#else
  return (x << r) | (x >> (32 - r));
#endif
}

// JAX threefry2x32, key=(0,42), partitionable: out = x0^x1 for ctr=(0,i).
// Input: x1 = i + 42 (key-add prefolded). x0 starts 0 so round-1 add = copy.
__device__ __forceinline__ uint32_t tf_from_init(uint32_t x1) {
  uint32_t x0 = x1;
  x1 = rotl(x1, 13) ^ x0;
  x0 += x1; x1 = rotl(x1, 15) ^ x0;
  x0 += x1; x1 = rotl(x1, 26) ^ x0;
  x0 += x1; x1 = rotl(x1,  6) ^ x0;
  x0 += 42u;          x1 += 0x1BD11BF1u;  // ks1, ks2+1
  x0 += x1; x1 = rotl(x1, 17) ^ x0;
  x0 += x1; x1 = rotl(x1, 29) ^ x0;
  x0 += x1; x1 = rotl(x1, 16) ^ x0;
  x0 += x1; x1 = rotl(x1, 24) ^ x0;
  x0 += 0x1BD11BF0u;  x1 += 2u;           // ks2, ks0+2
  x0 += x1; x1 = rotl(x1, 13) ^ x0;
  x0 += x1; x1 = rotl(x1, 15) ^ x0;
  x0 += x1; x1 = rotl(x1, 26) ^ x0;
  x0 += x1; x1 = rotl(x1,  6) ^ x0;
  /* ks0 = 0 */       x1 += 45u;          // ks1+3
  x0 += x1; x1 = rotl(x1, 17) ^ x0;
  x0 += x1; x1 = rotl(x1, 29) ^ x0;
  x0 += x1; x1 = rotl(x1, 16) ^ x0;
  x0 += x1; x1 = rotl(x1, 24) ^ x0;
  x0 += 42u;          x1 += 0x1BD11BF4u;  // ks1, ks2+4
  x0 += x1; x1 = rotl(x1, 13) ^ x0;
  x0 += x1; x1 = rotl(x1, 15) ^ x0;
  x0 += x1; x1 = rotl(x1, 26) ^ x0;
  x0 += x1; x1 = rotl(x1,  6) ^ x0;
  x0 += 0x1BD11BF0u;  x1 += 5u;           // ks2, ks0+5
  return x0 ^ x1;
}

// score = sp - ln2*log2(-log2(2-f)), sp = s*invT - ln(ln2). Bit-exact vs ref
// (absmax 0, rounds 1-6). Zero-mantissa draw -> +inf (wins).
__device__ __forceinline__ float score_one(uint32_t bits, float sp) {
  uint32_t fb = (bits >> 9) | 0x3F800000u;
  float q = 2.0f - __uint_as_float(fb);
  float t = __log2f(q);
  float l = __log2f(-t);                       // neg = free input modifier
  return __builtin_fmaf(l, -0.69314718f, sp);
}

__device__ __forceinline__ uint32_t order_f32(float sc) {
  uint32_t m = __float_as_uint(sc);
  return m ^ (uint32_t)(((int32_t)m >> 31) | 0x80000000);
}

#define SCORE(av, bv, JK)                                          \
  {                                                                \
    float sp = __builtin_fmaf((av), invT, 0.36651292f);            \
    float sc = score_one((bv), sp);                                \
    bestJK = (sc > bestS) ? (uint32_t)(JK) : bestJK;               \
    bestS = fmaxf(bestS, sc);                                      \
  }

__global__ __launch_bounds__(TPB, 4) void sample_main(
    const float* __restrict__ logits, const float* __restrict__ temps,
    unsigned long long* __restrict__ part) {
  const int b   = blockIdx.x;
  const int row = b / BPR;
  const int cb  = b - row * BPR;
  const int tcol = cb * BLOCK_COLS + (int)threadIdx.x * 4;

  const float invT = 1.0f / temps[row];
  const float* p0 = logits + (size_t)row * VOCAB + tcol;

  // Phase A: issue all 5 loads. The sched_barrier(0) below makes it illegal
  // for the scheduler to sink them into phase C (hipcc otherwise re-sinks
  // loads to minimize register pressure, recreating JIT-load latency
  // exposure — R4/R6 evidence). waitcnt placement is a separate pass, so
  // the waits still land late, covered by ~1400 cycles of phase B.
  const float4 a0 = *reinterpret_cast<const float4*>(p0);
  const float4 a1 = *reinterpret_cast<const float4*>(p0 + 1024);
  const float4 a2 = *reinterpret_cast<const float4*>(p0 + 2048);
  const float4 a3 = *reinterpret_cast<const float4*>(p0 + 3072);
  const float4 a4 = *reinterpret_cast<const float4*>(p0 + 4096);
  __builtin_amdgcn_sched_barrier(0);

  const uint32_t c42 = (uint32_t)row * (uint32_t)VOCAB + (uint32_t)tcol + 42u;

  // Phase B: all 20 threefry draws — independent of the loads.
  const uint32_t b0  = tf_from_init(c42 + 0u);
  const uint32_t b1  = tf_from_init(c42 + 1u);
  const uint32_t b2  = tf_from_init(c42 + 2u);
  const uint32_t b3  = tf_from_init(c42 + 3u);
  const uint32_t b4  = tf_from_init(c42 + 1024u);
  const uint32_t b5  = tf_from_init(c42 + 1025u);
  const uint32_t b6  = tf_from_init(c42 + 1026u);
  const uint32_t b7  = tf_from_init(c42 + 1027u);
  const uint32_t b8  = tf_from_init(c42 + 2048u);
  const uint32_t b9  = tf_from_init(c42 + 2049u);
  const uint32_t b10 = tf_from_init(c42 + 2050u);
  const uint32_t b11 = tf_from_init(c42 + 2051u);
  const uint32_t b12 = tf_from_init(c42 + 3072u);
  const uint32_t b13 = tf_from_init(c42 + 3073u);
  const uint32_t b14 = tf_from_init(c42 + 3074u);
  const uint32_t b15 = tf_from_init(c42 + 3075u);
  const uint32_t b16 = tf_from_init(c42 + 4096u);
  const uint32_t b17 = tf_from_init(c42 + 4097u);
  const uint32_t b18 = tf_from_init(c42 + 4098u);
  const uint32_t b19 = tf_from_init(c42 + 4099u);

  // Phase C: scores + running argmax (strict >: earliest col wins ties)
  float bestS = -__builtin_inff();
  uint32_t bestJK = 0u;
  SCORE(a0.x, b0,  0)  SCORE(a0.y, b1,  1)  SCORE(a0.z, b2,  2)  SCORE(a0.w, b3,  3)
  SCORE(a1.x, b4,  4)  SCORE(a1.y, b5,  5)  SCORE(a1.z, b6,  6)  SCORE(a1.w, b7,  7)
  SCORE(a2.x, b8,  8)  SCORE(a2.y, b9,  9)  SCORE(a2.z, b10, 10) SCORE(a2.w, b11, 11)
  SCORE(a3.x, b12, 12) SCORE(a3.y, b13, 13) SCORE(a3.z, b14, 14) SCORE(a3.w, b15, 15)
  SCORE(a4.x, b16, 16) SCORE(a4.y, b17, 17) SCORE(a4.z, b18, 18) SCORE(a4.w, b19, 19)

  // reconstruct winning column; pack (orderable score, ~col)
  const uint32_t col = (uint32_t)tcol + ((bestJK >> 2) << 10) + (bestJK & 3u);
  unsigned long long p =
      ((unsigned long long)order_f32(bestS) << 32) | (uint32_t)(~col);

#pragma unroll
  for (int off = 32; off > 0; off >>= 1) {
    unsigned long long o = __shfl_down(p, off, 64);
    p = (o > p) ? o : p;
  }

  __shared__ unsigned long long sm[TPB / 64];
  if ((threadIdx.x & 63) == 0) sm[threadIdx.x >> 6] = p;
  __syncthreads();
  if (threadIdx.x == 0) {
    unsigned long long bv = sm[0];
    bv = (sm[1] > bv) ? sm[1] : bv;
    bv = (sm[2] > bv) ? sm[2] : bv;
    bv = (sm[3] > bv) ? sm[3] : bv;
    part[b] = bv;
  }
}

__global__ __launch_bounds__(64) void reduce_rows(
    const unsigned long long* __restrict__ part, int* __restrict__ out) {
  const int r = blockIdx.x;
  const int t = threadIdx.x;
  unsigned long long bv = (t < BPR) ? part[r * BPR + t] : 0ull;
#pragma unroll
  for (int off = 32; off > 0; off >>= 1) {
    unsigned long long o = __shfl_down(bv, off, 64);
    bv = (o > bv) ? o : bv;
  }
  if (t == 0) out[r] = (int)(~(uint32_t)(bv & 0xFFFFFFFFull));
}

extern "C" void kernel_launch(void* const* d_in, const int* in_sizes, int n_in,
                              void* d_out, int out_size, void* d_ws, size_t ws_size,
                              hipStream_t stream) {
  const float* logits = (const float*)d_in[0];
  const float* temps  = (const float*)d_in[1];
  unsigned long long* part = (unsigned long long*)d_ws;  // 3200*8B = 25.6 KB
  int* out = (int*)d_out;

  hipLaunchKernelGGL(sample_main, dim3(GRID_A), dim3(TPB), 0, stream,
                     logits, temps, part);
  hipLaunchKernelGGL(reduce_rows, dim3(BATCH), dim3(64), 0, stream, part, out);
}

// Round 8
// 112.858 us; speedup vs baseline: 1.0226x; 1.0141x over previous
//
#include <hip/hip_runtime.h>
#include <stdint.h>

#define BATCH 128
#define VOCAB 128000
#define TPB 256
#define BLOCK_COLS 8000                      // 16 blocks per row, within-row
#define CHUNKS_PER_ROW 16
#define GRID_A (BATCH * CHUNKS_PER_ROW)      // 2048 = exactly 8 blocks/CU
#define REM_THREADS 208                      // (8000 - 7*1024)/4

__device__ __forceinline__ uint32_t rotl(uint32_t x, int r) {
#if __has_builtin(__builtin_rotateleft32)
  return __builtin_rotateleft32(x, (uint32_t)r);
#else
  return (x << r) | (x >> (32 - r));
#endif
}

// JAX threefry2x32, key=(0,42), partitionable: out = x0^x1 for ctr=(0,i).
// Input: x1 = i + 42 (key-add prefolded). x0 starts 0 so round-1 add = copy.
__device__ __forceinline__ uint32_t tf_from_init(uint32_t x1) {
  uint32_t x0 = x1;
  x1 = rotl(x1, 13) ^ x0;
  x0 += x1; x1 = rotl(x1, 15) ^ x0;
  x0 += x1; x1 = rotl(x1, 26) ^ x0;
  x0 += x1; x1 = rotl(x1,  6) ^ x0;
  x0 += 42u;          x1 += 0x1BD11BF1u;  // ks1, ks2+1
  x0 += x1; x1 = rotl(x1, 17) ^ x0;
  x0 += x1; x1 = rotl(x1, 29) ^ x0;
  x0 += x1; x1 = rotl(x1, 16) ^ x0;
  x0 += x1; x1 = rotl(x1, 24) ^ x0;
  x0 += 0x1BD11BF0u;  x1 += 2u;           // ks2, ks0+2
  x0 += x1; x1 = rotl(x1, 13) ^ x0;
  x0 += x1; x1 = rotl(x1, 15) ^ x0;
  x0 += x1; x1 = rotl(x1, 26) ^ x0;
  x0 += x1; x1 = rotl(x1,  6) ^ x0;
  /* ks0 = 0 */       x1 += 45u;          // ks1+3
  x0 += x1; x1 = rotl(x1, 17) ^ x0;
  x0 += x1; x1 = rotl(x1, 29) ^ x0;
  x0 += x1; x1 = rotl(x1, 16) ^ x0;
  x0 += x1; x1 = rotl(x1, 24) ^ x0;
  x0 += 42u;          x1 += 0x1BD11BF4u;  // ks1, ks2+4
  x0 += x1; x1 = rotl(x1, 13) ^ x0;
  x0 += x1; x1 = rotl(x1, 15) ^ x0;
  x0 += x1; x1 = rotl(x1, 26) ^ x0;
  x0 += x1; x1 = rotl(x1,  6) ^ x0;
  x0 += 0x1BD11BF0u;  x1 += 5u;           // ks2, ks0+5
  return x0 ^ x1;
}

// score = sp - ln2*log2(-log2(2-f)), sp = s*invT - ln(ln2). Bit-exact vs ref
// (absmax 0, rounds 1-7). Zero-mantissa draw -> +inf (wins).
__device__ __forceinline__ float score_one(uint32_t bits, float sp) {
  uint32_t fb = (bits >> 9) | 0x3F800000u;
  float q = 2.0f - __uint_as_float(fb);
  float t = __log2f(q);
  float l = __log2f(-t);                       // neg = free input modifier
  return __builtin_fmaf(l, -0.69314718f, sp);
}

__device__ __forceinline__ uint32_t order_f32(float sc) {
  uint32_t m = __float_as_uint(sc);
  return m ^ (uint32_t)(((int32_t)m >> 31) | 0x80000000);
}

#define SCORE(av, bv, JK)                                          \
  {                                                                \
    float sp = __builtin_fmaf((av), invT, 0.36651292f);            \
    float sc = score_one((bv), sp);                                \
    bestJK = (sc > bestS) ? (uint32_t)(JK) : bestJK;               \
    bestS = fmaxf(bestS, sc);                                      \
  }

// 4 elements from one float4, all-literal counter offsets and slot ids
#define ELEM4(av, OFF, JB)                                         \
  SCORE((av).x, tf_from_init(c42 + (uint32_t)(OFF) + 0u), (JB) + 0) \
  SCORE((av).y, tf_from_init(c42 + (uint32_t)(OFF) + 1u), (JB) + 1) \
  SCORE((av).z, tf_from_init(c42 + (uint32_t)(OFF) + 2u), (JB) + 2) \
  SCORE((av).w, tf_from_init(c42 + (uint32_t)(OFF) + 3u), (JB) + 3)

__global__ __launch_bounds__(TPB, 8) void sample_main(
    const float* __restrict__ logits, const float* __restrict__ temps,
    unsigned long long* __restrict__ part) {
  const int b     = blockIdx.x;           // 0..2047
  const int row   = b >> 4;               // 16 chunks per row
  const int chunk = b & 15;
  const int tcol  = chunk * BLOCK_COLS + (int)threadIdx.x * 4;  // within-row col

  const float invT = 1.0f / temps[row];
  const float* p0 = logits + (size_t)row * VOCAB + tcol;
  const uint32_t c42 = (uint32_t)row * (uint32_t)VOCAB + (uint32_t)tcol + 42u;

  float bestS = -__builtin_inff();
  uint32_t bestJK = 0u;

  // 7 full float4 groups at stride 1024 floats (coalesced per wave)
  const float4 g0 = *reinterpret_cast<const float4*>(p0);
  const float4 g1 = *reinterpret_cast<const float4*>(p0 + 1024);
  const float4 g2 = *reinterpret_cast<const float4*>(p0 + 2048);
  const float4 g3 = *reinterpret_cast<const float4*>(p0 + 3072);
  const float4 g4 = *reinterpret_cast<const float4*>(p0 + 4096);
  const float4 g5 = *reinterpret_cast<const float4*>(p0 + 5120);
  const float4 g6 = *reinterpret_cast<const float4*>(p0 + 6144);

  ELEM4(g0,    0,  0)
  ELEM4(g1, 1024,  4)
  ELEM4(g2, 2048,  8)
  ELEM4(g3, 3072, 12)
  ELEM4(g4, 4096, 16)
  ELEM4(g5, 5120, 20)
  ELEM4(g6, 6144, 24)

  // remainder group: cols 7168..7999 -> 208 threads; waves 4..15 skip whole
  if (threadIdx.x < REM_THREADS) {
    const float4 g7 = *reinterpret_cast<const float4*>(p0 + 7168);
    ELEM4(g7, 7168, 28)
  }

  // reconstruct winning within-row column; pack (orderable score, ~col)
  const uint32_t col = (uint32_t)tcol + ((bestJK >> 2) << 10) + (bestJK & 3u);
  unsigned long long p =
      ((unsigned long long)order_f32(bestS) << 32) | (uint32_t)(~col);

#pragma unroll
  for (int off = 32; off > 0; off >>= 1) {
    unsigned long long o = __shfl_down(p, off, 64);
    p = (o > p) ? o : p;
  }

  __shared__ unsigned long long sm[TPB / 64];
  if ((threadIdx.x & 63) == 0) sm[threadIdx.x >> 6] = p;
  __syncthreads();
  if (threadIdx.x == 0) {
    unsigned long long bv = sm[0];
    bv = (sm[1] > bv) ? sm[1] : bv;
    bv = (sm[2] > bv) ? sm[2] : bv;
    bv = (sm[3] > bv) ? sm[3] : bv;
    part[b] = bv;
  }
}

__global__ __launch_bounds__(64) void reduce_rows(
    const unsigned long long* __restrict__ part, int* __restrict__ out) {
  const int r = blockIdx.x;
  const int t = threadIdx.x;
  unsigned long long bv =
      (t < CHUNKS_PER_ROW) ? part[r * CHUNKS_PER_ROW + t] : 0ull;
#pragma unroll
  for (int off = 32; off > 0; off >>= 1) {
    unsigned long long o = __shfl_down(bv, off, 64);
    bv = (o > bv) ? o : bv;
  }
  if (t == 0) out[r] = (int)(~(uint32_t)(bv & 0xFFFFFFFFull));
}

extern "C" void kernel_launch(void* const* d_in, const int* in_sizes, int n_in,
                              void* d_out, int out_size, void* d_ws, size_t ws_size,
                              hipStream_t stream) {
  const float* logits = (const float*)d_in[0];
  const float* temps  = (const float*)d_in[1];
  unsigned long long* part = (unsigned long long*)d_ws;  // 2048*8B = 16.4 KB
  int* out = (int*)d_out;

  hipLaunchKernelGGL(sample_main, dim3(GRID_A), dim3(TPB), 0, stream,
                     logits, temps, part);
  hipLaunchKernelGGL(reduce_rows, dim3(BATCH), dim3(64), 0, stream, part, out);
}

// Round 9
// 112.680 us; speedup vs baseline: 1.0242x; 1.0016x over previous
//
#include <hip/hip_runtime.h>
#include <stdint.h>

#define BATCH 128
#define VOCAB 128000
#define TPB 256
#define BLOCK_COLS 8000                      // 16 blocks per row, within-row
#define CHUNKS_PER_ROW 16
#define GRID_A (BATCH * CHUNKS_PER_ROW)      // 2048 = exactly 8 blocks/CU
#define REM_THREADS 208                      // (8000 - 7*1024)/4

// rotl as a single v_alignbit_b32: alignbit(x,x,32-r) = (x:x)>>(32-r) = rotl(x,r)
#if __has_builtin(__builtin_amdgcn_alignbit)
#define ROTL(x, r) __builtin_amdgcn_alignbit((x), (x), 32 - (r))
#else
#define ROTL(x, r) (((x) << (r)) | ((x) >> (32 - (r))))
#endif

// JAX threefry2x32, key=(0,42), partitionable: out = x0^x1 for ctr=(0,i).
// Input: x1 = i + 42 (key-add prefolded). x0 starts 0 so round-1 add = copy.
__device__ __forceinline__ uint32_t tf_from_init(uint32_t x1) {
  uint32_t x0 = x1;
  x1 = ROTL(x1, 13) ^ x0;
  x0 += x1; x1 = ROTL(x1, 15) ^ x0;
  x0 += x1; x1 = ROTL(x1, 26) ^ x0;
  x0 += x1; x1 = ROTL(x1,  6) ^ x0;
  x0 += 42u;          x1 += 0x1BD11BF1u;  // ks1, ks2+1
  x0 += x1; x1 = ROTL(x1, 17) ^ x0;
  x0 += x1; x1 = ROTL(x1, 29) ^ x0;
  x0 += x1; x1 = ROTL(x1, 16) ^ x0;
  x0 += x1; x1 = ROTL(x1, 24) ^ x0;
  x0 += 0x1BD11BF0u;  x1 += 2u;           // ks2, ks0+2
  x0 += x1; x1 = ROTL(x1, 13) ^ x0;
  x0 += x1; x1 = ROTL(x1, 15) ^ x0;
  x0 += x1; x1 = ROTL(x1, 26) ^ x0;
  x0 += x1; x1 = ROTL(x1,  6) ^ x0;
  /* ks0 = 0 */       x1 += 45u;          // ks1+3
  x0 += x1; x1 = ROTL(x1, 17) ^ x0;
  x0 += x1; x1 = ROTL(x1, 29) ^ x0;
  x0 += x1; x1 = ROTL(x1, 16) ^ x0;
  x0 += x1; x1 = ROTL(x1, 24) ^ x0;
  x0 += 42u;          x1 += 0x1BD11BF4u;  // ks1, ks2+4
  x0 += x1; x1 = ROTL(x1, 13) ^ x0;
  x0 += x1; x1 = ROTL(x1, 15) ^ x0;
  x0 += x1; x1 = ROTL(x1, 26) ^ x0;
  x0 += x1; x1 = ROTL(x1,  6) ^ x0;
  x0 += 0x1BD11BF0u;  x1 += 5u;           // ks2, ks0+5
  return x0 ^ x1;
}

// score = sp - ln2*log2(-log2(2-f)), sp = s*invT - ln(ln2). Bit-exact vs ref
// (absmax 0, rounds 1-8). Zero-mantissa draw -> +inf (wins).
// fb pack fused: alignbit(0x7F, bits, 9) = (0x7F<<23)|(bits>>9) = 0x3F800000|(bits>>9)
__device__ __forceinline__ float score_one(uint32_t bits, float sp) {
#if __has_builtin(__builtin_amdgcn_alignbit)
  uint32_t fb = __builtin_amdgcn_alignbit(0x7Fu, bits, 9);
#else
  uint32_t fb = (bits >> 9) | 0x3F800000u;
#endif
  float q = 2.0f - __uint_as_float(fb);
  float t = __log2f(q);
  float l = __log2f(-t);                       // neg = free input modifier
  return __builtin_fmaf(l, -0.69314718f, sp);
}

__device__ __forceinline__ uint32_t order_f32(float sc) {
  uint32_t m = __float_as_uint(sc);
  return m ^ (uint32_t)(((int32_t)m >> 31) | 0x80000000);
}

#define SCORE(av, bv, JK)                                          \
  {                                                                \
    float sp = __builtin_fmaf((av), invT, 0.36651292f);            \
    float sc = score_one((bv), sp);                                \
    bestJK = (sc > bestS) ? (uint32_t)(JK) : bestJK;               \
    bestS = fmaxf(bestS, sc);                                      \
  }

// 4 elements from one float4, all-literal counter offsets and slot ids
#define ELEM4(av, OFF, JB)                                          \
  SCORE((av).x, tf_from_init(c42 + (uint32_t)(OFF) + 0u), (JB) + 0) \
  SCORE((av).y, tf_from_init(c42 + (uint32_t)(OFF) + 1u), (JB) + 1) \
  SCORE((av).z, tf_from_init(c42 + (uint32_t)(OFF) + 2u), (JB) + 2) \
  SCORE((av).w, tf_from_init(c42 + (uint32_t)(OFF) + 3u), (JB) + 3)

__global__ __launch_bounds__(TPB, 8) void sample_main(
    const float* __restrict__ logits, const float* __restrict__ temps,
    unsigned long long* __restrict__ part) {
  const int b     = blockIdx.x;           // 0..2047
  const int row   = b >> 4;               // 16 chunks per row
  const int chunk = b & 15;
  const int tcol  = chunk * BLOCK_COLS + (int)threadIdx.x * 4;  // within-row col

  const float invT = 1.0f / temps[row];
  const float* p0 = logits + (size_t)row * VOCAB + tcol;
  const uint32_t c42 = (uint32_t)row * (uint32_t)VOCAB + (uint32_t)tcol + 42u;

  float bestS = -__builtin_inff();
  uint32_t bestJK = 0u;

  // 7 full float4 groups at stride 1024 floats (coalesced per wave)
  const float4 g0 = *reinterpret_cast<const float4*>(p0);
  const float4 g1 = *reinterpret_cast<const float4*>(p0 + 1024);
  const float4 g2 = *reinterpret_cast<const float4*>(p0 + 2048);
  const float4 g3 = *reinterpret_cast<const float4*>(p0 + 3072);
  const float4 g4 = *reinterpret_cast<const float4*>(p0 + 4096);
  const float4 g5 = *reinterpret_cast<const float4*>(p0 + 5120);
  const float4 g6 = *reinterpret_cast<const float4*>(p0 + 6144);

  ELEM4(g0,    0,  0)
  ELEM4(g1, 1024,  4)
  ELEM4(g2, 2048,  8)
  ELEM4(g3, 3072, 12)
  ELEM4(g4, 4096, 16)
  ELEM4(g5, 5120, 20)
  ELEM4(g6, 6144, 24)

  // remainder group: cols 7168..7999 -> 208 threads; waves 4..15 skip whole
  if (threadIdx.x < REM_THREADS) {
    const float4 g7 = *reinterpret_cast<const float4*>(p0 + 7168);
    ELEM4(g7, 7168, 28)
  }

  // reconstruct winning within-row column; pack (orderable score, ~col)
  const uint32_t col = (uint32_t)tcol + ((bestJK >> 2) << 10) + (bestJK & 3u);
  unsigned long long p =
      ((unsigned long long)order_f32(bestS) << 32) | (uint32_t)(~col);

#pragma unroll
  for (int off = 32; off > 0; off >>= 1) {
    unsigned long long o = __shfl_down(p, off, 64);
    p = (o > p) ? o : p;
  }

  __shared__ unsigned long long sm[TPB / 64];
  if ((threadIdx.x & 63) == 0) sm[threadIdx.x >> 6] = p;
  __syncthreads();
  if (threadIdx.x == 0) {
    unsigned long long bv = sm[0];
    bv = (sm[1] > bv) ? sm[1] : bv;
    bv = (sm[2] > bv) ? sm[2] : bv;
    bv = (sm[3] > bv) ? sm[3] : bv;
    part[b] = bv;
  }
}

__global__ __launch_bounds__(64) void reduce_rows(
    const unsigned long long* __restrict__ part, int* __restrict__ out) {
  const int r = blockIdx.x;
  const int t = threadIdx.x;
  unsigned long long bv =
      (t < CHUNKS_PER_ROW) ? part[r * CHUNKS_PER_ROW + t] : 0ull;
#pragma unroll
  for (int off = 32; off > 0; off >>= 1) {
    unsigned long long o = __shfl_down(bv, off, 64);
    bv = (o > bv) ? o : bv;
  }
  if (t == 0) out[r] = (int)(~(uint32_t)(bv & 0xFFFFFFFFull));
}

extern "C" void kernel_launch(void* const* d_in, const int* in_sizes, int n_in,
                              void* d_out, int out_size, void* d_ws, size_t ws_size,
                              hipStream_t stream) {
  const float* logits = (const float*)d_in[0];
  const float* temps  = (const float*)d_in[1];
  unsigned long long* part = (unsigned long long*)d_ws;  // 2048*8B = 16.4 KB
  int* out = (int*)d_out;

  hipLaunchKernelGGL(sample_main, dim3(GRID_A), dim3(TPB), 0, stream,
                     logits, temps, part);
  hipLaunchKernelGGL(reduce_rows, dim3(BATCH), dim3(64), 0, stream, part, out);
}